// Round 5
// baseline (241.725 us; speedup 1.0000x reference)
//
#include <hip/hip_runtime.h>
#include <hip/hip_fp16.h>

#define B 8
#define H 160
#define W 160
#define D 96
#define S 64
#define ST_RATIO 1.5f

// ---------------------------------------------------------------------------
// Pass 1: streaming transpose vol [B,H,W,D] f32 -> volT [B,H,D,W] fp16.
// Block = one 32-wide w-chunk of one (b,h) plane. 6.3 KB LDS, 6400 blocks.
// ---------------------------------------------------------------------------
__global__ __launch_bounds__(256) void v2s_prep(
    const float* __restrict__ vol, __half* __restrict__ volT)
{
    __shared__ __half ph[32][98];          // [w_local][d], 49-word rows (odd)
    const int blk = blockIdx.x;            // B*H*5 = 6400
    const int bh  = blk / 5;
    const int w0  = (blk - bh * 5) * 32;
    const float* in = vol + ((size_t)bh * W + w0) * D;

    // read 32 rows x 96 f32 (768 float4, coalesced), convert to fp16 in LDS
    for (int i = threadIdx.x; i < 32 * 24; i += 256) {
        const int wl = i / 24, k = i - wl * 24;
        const float4 f = *(const float4*)(in + wl * D + 4 * k);
        __half2* dst = (__half2*)&ph[wl][4 * k];
        dst[0] = __floats2half2_rn(f.x, f.y);
        dst[1] = __floats2half2_rn(f.z, f.w);
    }
    __syncthreads();

    // write volT[bh][d][w0..w0+32): half2 stores, 16 lanes per d-row (64B runs)
    __half* op = volT + (size_t)bh * (D * W) + w0;
    for (int i = threadIdx.x; i < D * 16; i += 256) {
        const int d = i >> 4, k = i & 15;
        __half2 v;
        v.x = ph[2 * k][d];
        v.y = ph[2 * k + 1][d];
        *(__half2*)(op + d * W + 2 * k) = v;
    }
}

// ---------------------------------------------------------------------------
// Pass 2: sampling with 4-way s-ILP, direct float4 stores (no outT staging).
// Block = 128 hw x 64 s, 4 waves: wave -> (hw half, s half). 1600 blocks =
// 6.25/CU, one dispatch round. Wave lanes = 64 consecutive hw at uniform s
// -> near-contiguous gathers in [B,H,D,W]; per-batch volT ~4.9 MB ~ L2.
// ---------------------------------------------------------------------------
__global__ __launch_bounds__(256) void v2s_main2(
    const __half* __restrict__ volT,   // [B,H,D,W]
    const float*  __restrict__ trf,    // [B,S,12]
    float*        __restrict__ out)    // [B,H,W,S]
{
    __shared__ float As[S * 12];

    const int bid = blockIdx.x;                    // 1600 = 8*200
    const int t   = (bid & 7) * 200 + (bid >> 3);  // XCD <-> batch swizzle
    const int b   = t / 200;
    const int hwb = (t - b * 200) * 128;

    const float* tb = trf + (size_t)b * (S * 12);
    for (int e = threadIdx.x; e < S * 12; e += 256) {
        const int j = e % 12;
        float v = tb[e];
        if ((j & 3) == (j >> 2)) v += 1.0f;        // + eye(4)[:3,:]
        As[e] = v;
    }
    __syncthreads();

    const int lane = threadIdx.x & 63;
    const int wid  = threadIdx.x >> 6;
    const int hw   = hwb + (wid & 1) * 64 + lane;
    const int sb0  = (wid >> 1) * 32;
    const int h    = hw / W;
    const int w    = hw - h * W;
    const float fh = (float)h, fw = (float)w;
    const __half* vb = volT + (size_t)b * (H * D * W);
    float* ob = out + ((size_t)b * (H * W) + hw) * S;

    for (int it = 0; it < 8; ++it) {
        const int s0 = sb0 + it * 4;
        float res[4];
#pragma unroll
        for (int q = 0; q < 4; ++q) {
            const int s = s0 + q;
            const float* a = &As[s * 12];
            const float fz = (float)s * ST_RATIO;

            float x = fmaf(a[0], fh, fmaf(a[1], fw, fmaf(a[2],  fz, a[3])));
            float y = fmaf(a[4], fh, fmaf(a[5], fw, fmaf(a[6],  fz, a[7])));
            float z = fmaf(a[8], fh, fmaf(a[9], fw, fmaf(a[10], fz, a[11])));

            x = fminf(fmaxf(x, 0.0f), (float)(H - 1));
            y = fminf(fmaxf(y, 0.0f), (float)(W - 1));
            z = fminf(fmaxf(z, 0.0f), (float)(D - 1));

            const float flx = floorf(x), fly = floorf(y), flz = floorf(z);
            const float dx = x - flx, dy = y - fly, dz = z - flz;
            const int ix0 = (int)flx, iy0 = (int)fly, iz0 = (int)flz;
            const int ix1 = min(ix0 + 1, H - 1);
            const int iy1 = min(iy0 + 1, W - 1);
            const int iz1 = min(iz0 + 1, D - 1);

            const __half* p00 = vb + (ix0 * D + iz0) * W;
            const __half* p01 = vb + (ix0 * D + iz1) * W;
            const __half* p10 = vb + (ix1 * D + iz0) * W;
            const __half* p11 = vb + (ix1 * D + iz1) * W;

            const float v000 = __half2float(p00[iy0]), v001 = __half2float(p00[iy1]);
            const float v010 = __half2float(p01[iy0]), v011 = __half2float(p01[iy1]);
            const float v100 = __half2float(p10[iy0]), v101 = __half2float(p10[iy1]);
            const float v110 = __half2float(p11[iy0]), v111 = __half2float(p11[iy1]);

            const float c00 = fmaf(dy, v001 - v000, v000);
            const float c01 = fmaf(dy, v011 - v010, v010);
            const float c10 = fmaf(dy, v101 - v100, v100);
            const float c11 = fmaf(dy, v111 - v110, v110);
            const float c0  = fmaf(dz, c01 - c00, c00);
            const float c1  = fmaf(dz, c11 - c10, c10);
            res[q] = fmaf(dx, c1 - c0, c0);
        }
        float4 v4;
        v4.x = res[0]; v4.y = res[1]; v4.z = res[2]; v4.w = res[3];
        *(float4*)(ob + s0) = v4;                  // aligned; merges in L2
    }
}

// ---------------------------------------------------------------------------
// Fallback: direct f32 gather (R1) if workspace is too small.
// ---------------------------------------------------------------------------
__global__ __launch_bounds__(256) void v2s_fallback(
    const float* __restrict__ vol, const float* __restrict__ trf,
    float* __restrict__ out)
{
    __shared__ float As[S * 13];
    const int pos0 = blockIdx.x * 4;
    const int b = pos0 / (H * W);
    const float* tb = trf + (size_t)b * S * 12;
    for (int e = threadIdx.x; e < S * 12; e += 256) {
        int s = e / 12, j = e - s * 12;
        float v = tb[e];
        if ((j & 3) == (j >> 2)) v += 1.0f;
        As[s * 13 + j] = v;
    }
    __syncthreads();
    const int s   = threadIdx.x & 63;
    const int pos = pos0 + (threadIdx.x >> 6);
    const int hw  = pos % (H * W);
    const int h   = hw / W;
    const int w   = hw - h * W;
    const float* a = &As[s * 13];
    const float fh = (float)h, fw = (float)w, fz = (float)s * ST_RATIO;
    float x = fmaf(a[0], fh, fmaf(a[1], fw, fmaf(a[2],  fz, a[3])));
    float y = fmaf(a[4], fh, fmaf(a[5], fw, fmaf(a[6],  fz, a[7])));
    float z = fmaf(a[8], fh, fmaf(a[9], fw, fmaf(a[10], fz, a[11])));
    x = fminf(fmaxf(x, 0.0f), (float)(H - 1));
    y = fminf(fmaxf(y, 0.0f), (float)(W - 1));
    z = fminf(fmaxf(z, 0.0f), (float)(D - 1));
    const float flx = floorf(x), fly = floorf(y), flz = floorf(z);
    const float dx = x - flx, dy = y - fly, dz = z - flz;
    const int ix0 = (int)flx, iy0 = (int)fly, iz0 = (int)flz;
    const int ix1 = min(ix0 + 1, H - 1);
    const int iy1 = min(iy0 + 1, W - 1);
    const int iz1 = min(iz0 + 1, D - 1);
    const float* vb  = vol + (size_t)b * (H * W * D);
    const float* p00 = vb + (ix0 * W + iy0) * D;
    const float* p01 = vb + (ix0 * W + iy1) * D;
    const float* p10 = vb + (ix1 * W + iy0) * D;
    const float* p11 = vb + (ix1 * W + iy1) * D;
    const float v000 = p00[iz0], v001 = p00[iz1];
    const float v010 = p01[iz0], v011 = p01[iz1];
    const float v100 = p10[iz0], v101 = p10[iz1];
    const float v110 = p11[iz0], v111 = p11[iz1];
    const float c00 = fmaf(dz, v001 - v000, v000);
    const float c01 = fmaf(dz, v011 - v010, v010);
    const float c10 = fmaf(dz, v101 - v100, v100);
    const float c11 = fmaf(dz, v111 - v110, v110);
    const float c0  = fmaf(dy, c01 - c00, c00);
    const float c1  = fmaf(dy, c11 - c10, c10);
    out[(size_t)pos * S + s] = fmaf(dx, c1 - c0, c0);
}

extern "C" void kernel_launch(void* const* d_in, const int* in_sizes, int n_in,
                              void* d_out, int out_size, void* d_ws, size_t ws_size,
                              hipStream_t stream) {
    const float* vol = (const float*)d_in[0];
    const float* trf = (const float*)d_in[1];
    float* out = (float*)d_out;

    const size_t volT_bytes = (size_t)B * H * D * W * sizeof(__half);  // 39.3 MB
    if (ws_size >= volT_bytes) {
        __half* volT = (__half*)d_ws;
        v2s_prep<<<B * H * 5, 256, 0, stream>>>(vol, volT);
        v2s_main2<<<1600, 256, 0, stream>>>(volT, trf, out);
    } else {
        v2s_fallback<<<(B * H * W) / 4, 256, 0, stream>>>(vol, trf, out);
    }
}

// Round 6
// 207.339 us; speedup vs baseline: 1.1658x; 1.1658x over previous
//
#include <hip/hip_runtime.h>
#include <hip/hip_fp16.h>

#define B 8
#define H 160
#define W 160
#define D 96
#define S 64
#define ST_RATIO 1.5f

// ---------------------------------------------------------------------------
// Prep: vol [B,H,W,D] f32 -> volT [B,H,D,W] fp16.
// One block per (b,h) plane (1280 blocks x 512 thr, 33.9 KB LDS -> 4 blk/CU
// x 8 waves = 32 waves/CU). Reads: fully-coalesced float4 (plane is one
// contiguous 240 KB run). Writes: half2, 256 B/wave contiguous.
// ---------------------------------------------------------------------------
__global__ __launch_bounds__(512) void v2s_prep2(
    const float* __restrict__ vol, __half* __restrict__ volT)
{
    __shared__ __half ph[W * 106];   // [w][d] rows padded to 106 halves (53 words, odd)
    const int bh = blockIdx.x;       // B*H = 1280
    const float* in = vol + (size_t)bh * (W * D);

    for (int i = threadIdx.x; i < W * (D / 4); i += 512) {
        const int w_ = i / 24, k = i - w_ * 24;
        const float4 f = *(const float4*)(in + w_ * D + 4 * k);
        __half2* dst = (__half2*)&ph[w_ * 106 + 4 * k];
        dst[0] = __floats2half2_rn(f.x, f.y);
        dst[1] = __floats2half2_rn(f.z, f.w);
    }
    __syncthreads();

    __half* op = volT + (size_t)bh * (D * W);
    for (int i = threadIdx.x; i < D * (W / 2); i += 512) {
        const int d = i / 80, k = i - d * 80;
        __half2 v;
        v.x = ph[(2 * k) * 106 + d];
        v.y = ph[(2 * k + 1) * 106 + d];
        *(__half2*)(op + d * W + 2 * k) = v;
    }
}

// ---------------------------------------------------------------------------
// Main (R2 structure, measured 72 us): wave = 64 consecutive hw at ONE s ->
// near-contiguous gathers in [B,H,D,W]; per-batch volT ~4.9 MB ~ L2-resident
// with XCD<->batch swizzle. Output staged in LDS, written lanes-along-s
// (coalesced). A-rows read from global trf via wave-uniform scalar loads;
// identity folded: x = fh + dot(a_row, g).
// ---------------------------------------------------------------------------
__global__ __launch_bounds__(256) void v2s_main3(
    const __half* __restrict__ volT,   // [B,H,D,W]
    const float*  __restrict__ trf,    // [B,S,12]
    float*        __restrict__ out)    // [B,H,W,S]
{
    __shared__ float outT[64][65];

    const int bid  = blockIdx.x;                   // 3200 = 8*400
    const int tile = (bid & 7) * 400 + (bid >> 3); // XCD <-> batch swizzle
    const int b    = tile / 400;
    const int hw0  = (tile - b * 400) * 64;

    const int lane = threadIdx.x & 63;
    const int wid  = threadIdx.x >> 6;
    const int hw   = hw0 + lane;
    const int h    = hw / W;
    const int w    = hw - h * W;
    const float fh = (float)h, fw = (float)w;
    const __half* vb = volT + (size_t)b * (H * D * W);
    const float* tb  = trf + (size_t)b * (S * 12);

#pragma unroll 4
    for (int it = 0; it < 16; ++it) {
        const int s = it * 4 + wid;                // wave-uniform slice
        const float* a = tb + s * 12;              // uniform -> s_load
        const float fz = (float)s * ST_RATIO;

        float x = fh + fmaf(a[0], fh, fmaf(a[1], fw, fmaf(a[2],  fz, a[3])));
        float y = fw + fmaf(a[4], fh, fmaf(a[5], fw, fmaf(a[6],  fz, a[7])));
        float z = fz + fmaf(a[8], fh, fmaf(a[9], fw, fmaf(a[10], fz, a[11])));

        x = fminf(fmaxf(x, 0.0f), (float)(H - 1));
        y = fminf(fmaxf(y, 0.0f), (float)(W - 1));
        z = fminf(fmaxf(z, 0.0f), (float)(D - 1));

        const float flx = floorf(x), fly = floorf(y), flz = floorf(z);
        const float dx = x - flx, dy = y - fly, dz = z - flz;
        const int ix0 = (int)flx, iy0 = (int)fly, iz0 = (int)flz;
        const int ix1 = min(ix0 + 1, H - 1);
        const int iy1 = min(iy0 + 1, W - 1);
        const int iz1 = min(iz0 + 1, D - 1);

        const __half* p00 = vb + (ix0 * D + iz0) * W;
        const __half* p01 = vb + (ix0 * D + iz1) * W;
        const __half* p10 = vb + (ix1 * D + iz0) * W;
        const __half* p11 = vb + (ix1 * D + iz1) * W;

        const float v000 = __half2float(p00[iy0]), v001 = __half2float(p00[iy1]);
        const float v010 = __half2float(p01[iy0]), v011 = __half2float(p01[iy1]);
        const float v100 = __half2float(p10[iy0]), v101 = __half2float(p10[iy1]);
        const float v110 = __half2float(p11[iy0]), v111 = __half2float(p11[iy1]);

        const float c00 = fmaf(dy, v001 - v000, v000);
        const float c01 = fmaf(dy, v011 - v010, v010);
        const float c10 = fmaf(dy, v101 - v100, v100);
        const float c11 = fmaf(dy, v111 - v110, v110);
        const float c0  = fmaf(dz, c01 - c00, c00);
        const float c1  = fmaf(dz, c11 - c10, c10);
        outT[lane][s]   = fmaf(dx, c1 - c0, c0);
    }
    __syncthreads();

    const int s_out = lane;
#pragma unroll
    for (int r = 0; r < 16; ++r) {
        const int hw_off = wid + 4 * r;
        out[((size_t)(b * (H * W) + hw0 + hw_off)) * S + s_out] = outT[hw_off][s_out];
    }
}

// ---------------------------------------------------------------------------
// Fallback: direct f32 gather (R1) if workspace is too small.
// ---------------------------------------------------------------------------
__global__ __launch_bounds__(256) void v2s_fallback(
    const float* __restrict__ vol, const float* __restrict__ trf,
    float* __restrict__ out)
{
    __shared__ float As[S * 13];
    const int pos0 = blockIdx.x * 4;
    const int b = pos0 / (H * W);
    const float* tb = trf + (size_t)b * S * 12;
    for (int e = threadIdx.x; e < S * 12; e += 256) {
        int s = e / 12, j = e - s * 12;
        float v = tb[e];
        if ((j & 3) == (j >> 2)) v += 1.0f;
        As[s * 13 + j] = v;
    }
    __syncthreads();
    const int s   = threadIdx.x & 63;
    const int pos = pos0 + (threadIdx.x >> 6);
    const int hw  = pos % (H * W);
    const int h   = hw / W;
    const int w   = hw - h * W;
    const float* a = &As[s * 13];
    const float fh = (float)h, fw = (float)w, fz = (float)s * ST_RATIO;
    float x = fmaf(a[0], fh, fmaf(a[1], fw, fmaf(a[2],  fz, a[3])));
    float y = fmaf(a[4], fh, fmaf(a[5], fw, fmaf(a[6],  fz, a[7])));
    float z = fmaf(a[8], fh, fmaf(a[9], fw, fmaf(a[10], fz, a[11])));
    x = fminf(fmaxf(x, 0.0f), (float)(H - 1));
    y = fminf(fmaxf(y, 0.0f), (float)(W - 1));
    z = fminf(fmaxf(z, 0.0f), (float)(D - 1));
    const float flx = floorf(x), fly = floorf(y), flz = floorf(z);
    const float dx = x - flx, dy = y - fly, dz = z - flz;
    const int ix0 = (int)flx, iy0 = (int)fly, iz0 = (int)flz;
    const int ix1 = min(ix0 + 1, H - 1);
    const int iy1 = min(iy0 + 1, W - 1);
    const int iz1 = min(iz0 + 1, D - 1);
    const float* vb  = vol + (size_t)b * (H * W * D);
    const float* p00 = vb + (ix0 * W + iy0) * D;
    const float* p01 = vb + (ix0 * W + iy1) * D;
    const float* p10 = vb + (ix1 * W + iy0) * D;
    const float* p11 = vb + (ix1 * W + iy1) * D;
    const float v000 = p00[iz0], v001 = p00[iz1];
    const float v010 = p01[iz0], v011 = p01[iz1];
    const float v100 = p10[iz0], v101 = p10[iz1];
    const float v110 = p11[iz0], v111 = p11[iz1];
    const float c00 = fmaf(dz, v001 - v000, v000);
    const float c01 = fmaf(dz, v011 - v010, v010);
    const float c10 = fmaf(dz, v101 - v100, v100);
    const float c11 = fmaf(dz, v111 - v110, v110);
    const float c0  = fmaf(dy, c01 - c00, c00);
    const float c1  = fmaf(dy, c11 - c10, c10);
    out[(size_t)pos * S + s] = fmaf(dx, c1 - c0, c0);
}

extern "C" void kernel_launch(void* const* d_in, const int* in_sizes, int n_in,
                              void* d_out, int out_size, void* d_ws, size_t ws_size,
                              hipStream_t stream) {
    const float* vol = (const float*)d_in[0];
    const float* trf = (const float*)d_in[1];
    float* out = (float*)d_out;

    const size_t volT_bytes = (size_t)B * H * D * W * sizeof(__half);  // 39.3 MB
    if (ws_size >= volT_bytes) {
        __half* volT = (__half*)d_ws;
        v2s_prep2<<<B * H, 512, 0, stream>>>(vol, volT);
        v2s_main3<<<3200, 256, 0, stream>>>(volT, trf, out);
    } else {
        v2s_fallback<<<(B * H * W) / 4, 256, 0, stream>>>(vol, trf, out);
    }
}

// Round 7
// 175.205 us; speedup vs baseline: 1.3797x; 1.1834x over previous
//
#include <hip/hip_runtime.h>
#include <hip/hip_fp16.h>

#define B 8
#define H 160
#define W 160
#define D 96
#define S 64
#define ST_RATIO 1.5f

// ---------------------------------------------------------------------------
// Prep: vol [B,H,W,D] f32 -> volP [B,H,D,W] of half2 {v(y), v(y+1 clamped)}.
// One block per (b,h) plane. Phase 1: coalesced float4 reads, transpose into
// LDS [d][w] (stride 164 halves -> 8B-aligned rows). Phase 2: ushort4 LDS
// reads + 16B global stores (4 entries per iter, 1 KB/wave contiguous).
// ---------------------------------------------------------------------------
__global__ __launch_bounds__(256) void v2s_prep3(
    const float* __restrict__ vol, __half2* __restrict__ volP)
{
    __shared__ __half ph[D * 164];       // [d][w], stride 164 halves (328 B)
    const int bh = blockIdx.x;           // B*H = 1280
    const float* in = vol + (size_t)bh * (W * D);

    // phase 1: read [w][d] coalesced along d, write transposed into LDS
    for (int i = threadIdx.x; i < W * (D / 4); i += 256) {
        const int w_ = i / 24, k = i - w_ * 24;      // D/4 = 24
        const float4 f = *(const float4*)(in + w_ * D + 4 * k);
        const int d0 = 4 * k;
        ph[(d0 + 0) * 164 + w_] = __float2half(f.x);
        ph[(d0 + 1) * 164 + w_] = __float2half(f.y);
        ph[(d0 + 2) * 164 + w_] = __float2half(f.z);
        ph[(d0 + 3) * 164 + w_] = __float2half(f.w);
    }
    __syncthreads();

    // phase 2: emit 4 y-pair entries (16 B) per iteration
    __half2* op = volP + (size_t)bh * (D * W);
    for (int i = threadIdx.x; i < D * (W / 4); i += 256) {
        const int d = i / 40, g = i - d * 40;        // W/4 = 40
        const int w0 = 4 * g;
        const __half* row = &ph[d * 164];
        const ushort4 a = *(const ushort4*)(row + w0);           // 8B aligned
        const unsigned a4 = (unsigned)__half_as_ushort(row[min(w0 + 4, W - 1)]);
        int4 o;
        o.x = (int)((unsigned)a.x | ((unsigned)a.y << 16));      // {v(w0),v(w0+1)}
        o.y = (int)((unsigned)a.y | ((unsigned)a.z << 16));      // {v(w0+1),v(w0+2)}
        o.z = (int)((unsigned)a.z | ((unsigned)a.w << 16));      // {v(w0+2),v(w0+3)}
        o.w = (int)((unsigned)a.w | (a4 << 16));                 // {v(w0+3),v(w0+4)}
        *(int4*)(op + (size_t)d * W + w0) = o;                   // 16B aligned
    }
}

// ---------------------------------------------------------------------------
// Main: R2's proven structure (As in LDS, outT staging, 3200 blocks,
// XCD<->batch swizzle) with y-pair loads: 4 aligned 4B gathers per sample.
// Wave = 64 consecutive hw at ONE s -> near-contiguous gathers.
// ---------------------------------------------------------------------------
__global__ __launch_bounds__(256) void v2s_main4(
    const __half2* __restrict__ volP,  // [B,H,D,W] y-pair entries
    const float*   __restrict__ trf,   // [B,S,12]
    float*         __restrict__ out)   // [B,H,W,S]
{
    __shared__ float As[S * 12];
    __shared__ float outT[64][65];

    const int bid  = blockIdx.x;                   // 3200 = 8*400
    const int tile = (bid & 7) * 400 + (bid >> 3); // XCD <-> batch swizzle
    const int b    = tile / 400;
    const int hw0  = (tile - b * 400) * 64;

    const float* tb = trf + (size_t)b * (S * 12);
    for (int e = threadIdx.x; e < S * 12; e += 256) {
        const int j = e % 12;
        float v = tb[e];
        if ((j & 3) == (j >> 2)) v += 1.0f;        // + eye(4)[:3,:]
        As[e] = v;
    }
    __syncthreads();

    const int lane = threadIdx.x & 63;
    const int wid  = threadIdx.x >> 6;
    const int hw   = hw0 + lane;
    const int h    = hw / W;
    const int w    = hw - h * W;
    const float fh = (float)h, fw = (float)w;
    const __half2* vb = volP + (size_t)b * (H * D * W);

#pragma unroll 4
    for (int it = 0; it < 16; ++it) {
        const int s = it * 4 + wid;                // wave-uniform slice
        const float* a = &As[s * 12];
        const float fz = (float)s * ST_RATIO;

        float x = fmaf(a[0], fh, fmaf(a[1], fw, fmaf(a[2],  fz, a[3])));
        float y = fmaf(a[4], fh, fmaf(a[5], fw, fmaf(a[6],  fz, a[7])));
        float z = fmaf(a[8], fh, fmaf(a[9], fw, fmaf(a[10], fz, a[11])));

        x = fminf(fmaxf(x, 0.0f), (float)(H - 1));
        y = fminf(fmaxf(y, 0.0f), (float)(W - 1));
        z = fminf(fmaxf(z, 0.0f), (float)(D - 1));

        const float flx = floorf(x), fly = floorf(y), flz = floorf(z);
        const float dx = x - flx, dy = y - fly, dz = z - flz;
        const int ix0 = (int)flx, iy0 = (int)fly, iz0 = (int)flz;
        const int ix1 = min(ix0 + 1, H - 1);
        const int iz1 = min(iz0 + 1, D - 1);

        // y-pair entries: one 4B load gives {v(y0), v(y0+1 clamped)}
        const int r0 = ix0 * D, r1 = ix1 * D;
        const float2 l00 = __half22float2(vb[(r0 + iz0) * W + iy0]);
        const float2 l01 = __half22float2(vb[(r0 + iz1) * W + iy0]);
        const float2 l10 = __half22float2(vb[(r1 + iz0) * W + iy0]);
        const float2 l11 = __half22float2(vb[(r1 + iz1) * W + iy0]);

        const float c00 = fmaf(dy, l00.y - l00.x, l00.x);
        const float c01 = fmaf(dy, l01.y - l01.x, l01.x);
        const float c10 = fmaf(dy, l10.y - l10.x, l10.x);
        const float c11 = fmaf(dy, l11.y - l11.x, l11.x);
        const float c0  = fmaf(dz, c01 - c00, c00);
        const float c1  = fmaf(dz, c11 - c10, c10);
        outT[lane][s]   = fmaf(dx, c1 - c0, c0);
    }
    __syncthreads();

    const int s_out = lane;
#pragma unroll
    for (int r = 0; r < 16; ++r) {
        const int hw_off = wid + 4 * r;
        out[((size_t)(b * (H * W) + hw0 + hw_off)) * S + s_out] = outT[hw_off][s_out];
    }
}

// ---------------------------------------------------------------------------
// Fallback: direct f32 gather (R1) if workspace is too small.
// ---------------------------------------------------------------------------
__global__ __launch_bounds__(256) void v2s_fallback(
    const float* __restrict__ vol, const float* __restrict__ trf,
    float* __restrict__ out)
{
    __shared__ float As[S * 13];
    const int pos0 = blockIdx.x * 4;
    const int b = pos0 / (H * W);
    const float* tb = trf + (size_t)b * S * 12;
    for (int e = threadIdx.x; e < S * 12; e += 256) {
        int s = e / 12, j = e - s * 12;
        float v = tb[e];
        if ((j & 3) == (j >> 2)) v += 1.0f;
        As[s * 13 + j] = v;
    }
    __syncthreads();
    const int s   = threadIdx.x & 63;
    const int pos = pos0 + (threadIdx.x >> 6);
    const int hw  = pos % (H * W);
    const int h   = hw / W;
    const int w   = hw - h * W;
    const float* a = &As[s * 13];
    const float fh = (float)h, fw = (float)w, fz = (float)s * ST_RATIO;
    float x = fmaf(a[0], fh, fmaf(a[1], fw, fmaf(a[2],  fz, a[3])));
    float y = fmaf(a[4], fh, fmaf(a[5], fw, fmaf(a[6],  fz, a[7])));
    float z = fmaf(a[8], fh, fmaf(a[9], fw, fmaf(a[10], fz, a[11])));
    x = fminf(fmaxf(x, 0.0f), (float)(H - 1));
    y = fminf(fmaxf(y, 0.0f), (float)(W - 1));
    z = fminf(fmaxf(z, 0.0f), (float)(D - 1));
    const float flx = floorf(x), fly = floorf(y), flz = floorf(z);
    const float dx = x - flx, dy = y - fly, dz = z - flz;
    const int ix0 = (int)flx, iy0 = (int)fly, iz0 = (int)flz;
    const int ix1 = min(ix0 + 1, H - 1);
    const int iy1 = min(iy0 + 1, W - 1);
    const int iz1 = min(iz0 + 1, D - 1);
    const float* vb  = vol + (size_t)b * (H * W * D);
    const float* p00 = vb + (ix0 * W + iy0) * D;
    const float* p01 = vb + (ix0 * W + iy1) * D;
    const float* p10 = vb + (ix1 * W + iy0) * D;
    const float* p11 = vb + (ix1 * W + iy1) * D;
    const float v000 = p00[iz0], v001 = p00[iz1];
    const float v010 = p01[iz0], v011 = p01[iz1];
    const float v100 = p10[iz0], v101 = p10[iz1];
    const float v110 = p11[iz0], v111 = p11[iz1];
    const float c00 = fmaf(dz, v001 - v000, v000);
    const float c01 = fmaf(dz, v011 - v010, v010);
    const float c10 = fmaf(dz, v101 - v100, v100);
    const float c11 = fmaf(dz, v111 - v110, v110);
    const float c0  = fmaf(dy, c01 - c00, c00);
    const float c1  = fmaf(dy, c11 - c10, c10);
    out[(size_t)pos * S + s] = fmaf(dx, c1 - c0, c0);
}

extern "C" void kernel_launch(void* const* d_in, const int* in_sizes, int n_in,
                              void* d_out, int out_size, void* d_ws, size_t ws_size,
                              hipStream_t stream) {
    const float* vol = (const float*)d_in[0];
    const float* trf = (const float*)d_in[1];
    float* out = (float*)d_out;

    const size_t volP_bytes = (size_t)B * H * D * W * sizeof(__half2);  // 78.6 MB
    if (ws_size >= volP_bytes) {
        __half2* volP = (__half2*)d_ws;
        v2s_prep3<<<B * H, 256, 0, stream>>>(vol, volP);
        v2s_main4<<<3200, 256, 0, stream>>>(volP, trf, out);
    } else {
        v2s_fallback<<<(B * H * W) / 4, 256, 0, stream>>>(vol, trf, out);
    }
}

// Round 8
// 174.782 us; speedup vs baseline: 1.3830x; 1.0024x over previous
//
#include <hip/hip_runtime.h>
#include <hip/hip_fp16.h>

#define B 8
#define H 160
#define W 160
#define D 96
#define S 64
#define ST_RATIO 1.5f

// ---------------------------------------------------------------------------
// Prep: vol [B,H,W,D] f32 -> volP [B,H,D,W] of half2 {v(y), v(y+1 clamped)}.
// One block per HALF (b,h) plane (2560 blocks, 16.1 KB LDS -> 8 blk/CU).
// Phase 1: coalesced float4 reads of 81 w-rows (80 + halo), transpose into
// LDS [d][w_local] (stride 84 halves = 168 B, 8B-aligned rows).
// Phase 2: ushort4 LDS reads + 16B global stores (4 y-pair entries/iter).
// ---------------------------------------------------------------------------
__global__ __launch_bounds__(256) void v2s_prep4(
    const float* __restrict__ vol, __half2* __restrict__ volP)
{
    __shared__ __half ph[D * 84];        // [d][w_local 0..80], stride 84
    const int blk   = blockIdx.x;        // B*H*2 = 2560
    const int bh    = blk >> 1;
    const int wbase = (blk & 1) * 80;
    const float* in = vol + (size_t)bh * (W * D);

    // phase 1: 81 rows (w = wbase..wbase+80, clamped), coalesced along d
    for (int i = threadIdx.x; i < 81 * (D / 4); i += 256) {
        const int rr = i / 24, k = i - rr * 24;          // D/4 = 24
        const int w_ = min(wbase + rr, W - 1);
        const float4 f = *(const float4*)(in + w_ * D + 4 * k);
        const int d0 = 4 * k;
        ph[(d0 + 0) * 84 + rr] = __float2half(f.x);
        ph[(d0 + 1) * 84 + rr] = __float2half(f.y);
        ph[(d0 + 2) * 84 + rr] = __float2half(f.z);
        ph[(d0 + 3) * 84 + rr] = __float2half(f.w);
    }
    __syncthreads();

    // phase 2: emit 4 y-pair entries (16 B) per iteration
    __half2* op = volP + (size_t)bh * (D * W) + wbase;
    for (int i = threadIdx.x; i < D * 20; i += 256) {    // 80/4 = 20 groups
        const int d = i / 20, g = i - d * 20;
        const int w0 = 4 * g;
        const __half* row = &ph[d * 84];
        const ushort4 a = *(const ushort4*)(row + w0);               // 8B aligned
        const unsigned a4 = (unsigned)__half_as_ushort(row[w0 + 4]); // halo col
        int4 o;
        o.x = (int)((unsigned)a.x | ((unsigned)a.y << 16));
        o.y = (int)((unsigned)a.y | ((unsigned)a.z << 16));
        o.z = (int)((unsigned)a.z | ((unsigned)a.w << 16));
        o.w = (int)((unsigned)a.w | (a4 << 16));
        *(int4*)(op + (size_t)d * W + w0) = o;                       // 16B aligned
    }
}

// ---------------------------------------------------------------------------
// Main: R2/R7 proven structure (As in LDS, outT staging, 3200 blocks,
// XCD<->batch swizzle), y-pair loads (4 aligned 4B gathers/sample), now with
// an explicit depth-2 software pipeline: iteration it+1's gathers are issued
// before iteration it is consumed (all statically unrolled).
// ---------------------------------------------------------------------------
struct Pk {
    float dx, dy, dz;
    __half2 v00, v01, v10, v11;
};

__device__ __forceinline__ Pk v2s_issue(
    const float* __restrict__ As, int s, float fh, float fw,
    const __half2* __restrict__ vb)
{
    const float* a = &As[s * 12];
    const float fz = (float)s * ST_RATIO;

    float x = fmaf(a[0], fh, fmaf(a[1], fw, fmaf(a[2],  fz, a[3])));
    float y = fmaf(a[4], fh, fmaf(a[5], fw, fmaf(a[6],  fz, a[7])));
    float z = fmaf(a[8], fh, fmaf(a[9], fw, fmaf(a[10], fz, a[11])));

    x = fminf(fmaxf(x, 0.0f), (float)(H - 1));
    y = fminf(fmaxf(y, 0.0f), (float)(W - 1));
    z = fminf(fmaxf(z, 0.0f), (float)(D - 1));

    const float flx = floorf(x), fly = floorf(y), flz = floorf(z);
    const int ix0 = (int)flx, iy0 = (int)fly, iz0 = (int)flz;
    const int ix1 = min(ix0 + 1, H - 1);
    const int iz1 = min(iz0 + 1, D - 1);
    const int r0 = ix0 * D, r1 = ix1 * D;

    Pk p;
    p.dx = x - flx; p.dy = y - fly; p.dz = z - flz;
    p.v00 = vb[(r0 + iz0) * W + iy0];   // loads issued here; consumed later
    p.v01 = vb[(r0 + iz1) * W + iy0];
    p.v10 = vb[(r1 + iz0) * W + iy0];
    p.v11 = vb[(r1 + iz1) * W + iy0];
    return p;
}

__global__ __launch_bounds__(256) void v2s_main5(
    const __half2* __restrict__ volP,  // [B,H,D,W] y-pair entries
    const float*   __restrict__ trf,   // [B,S,12]
    float*         __restrict__ out)   // [B,H,W,S]
{
    __shared__ float As[S * 12];
    __shared__ float outT[64][65];

    const int bid  = blockIdx.x;                   // 3200 = 8*400
    const int tile = (bid & 7) * 400 + (bid >> 3); // XCD <-> batch swizzle
    const int b    = tile / 400;
    const int hw0  = (tile - b * 400) * 64;

    const float* tb = trf + (size_t)b * (S * 12);
    for (int e = threadIdx.x; e < S * 12; e += 256) {
        const int j = e % 12;
        float v = tb[e];
        if ((j & 3) == (j >> 2)) v += 1.0f;        // + eye(4)[:3,:]
        As[e] = v;
    }
    __syncthreads();

    const int lane = threadIdx.x & 63;
    const int wid  = threadIdx.x >> 6;
    const int hw   = hw0 + lane;
    const int h    = hw / W;
    const int w    = hw - h * W;
    const float fh = (float)h, fw = (float)w;
    const __half2* vb = volP + (size_t)b * (H * D * W);

    Pk cur = v2s_issue(As, wid, fh, fw, vb);       // it = 0
#pragma unroll
    for (int it = 0; it < 16; ++it) {
        Pk nxt;
        if (it < 15) nxt = v2s_issue(As, (it + 1) * 4 + wid, fh, fw, vb);

        const float2 l00 = __half22float2(cur.v00);
        const float2 l01 = __half22float2(cur.v01);
        const float2 l10 = __half22float2(cur.v10);
        const float2 l11 = __half22float2(cur.v11);
        const float c00 = fmaf(cur.dy, l00.y - l00.x, l00.x);
        const float c01 = fmaf(cur.dy, l01.y - l01.x, l01.x);
        const float c10 = fmaf(cur.dy, l10.y - l10.x, l10.x);
        const float c11 = fmaf(cur.dy, l11.y - l11.x, l11.x);
        const float c0  = fmaf(cur.dz, c01 - c00, c00);
        const float c1  = fmaf(cur.dz, c11 - c10, c10);
        outT[lane][it * 4 + wid] = fmaf(cur.dx, c1 - c0, c0);

        cur = nxt;
    }
    __syncthreads();

    const int s_out = lane;
#pragma unroll
    for (int r = 0; r < 16; ++r) {
        const int hw_off = wid + 4 * r;
        out[((size_t)(b * (H * W) + hw0 + hw_off)) * S + s_out] = outT[hw_off][s_out];
    }
}

// ---------------------------------------------------------------------------
// Fallback: direct f32 gather (R1) if workspace is too small.
// ---------------------------------------------------------------------------
__global__ __launch_bounds__(256) void v2s_fallback(
    const float* __restrict__ vol, const float* __restrict__ trf,
    float* __restrict__ out)
{
    __shared__ float As[S * 13];
    const int pos0 = blockIdx.x * 4;
    const int b = pos0 / (H * W);
    const float* tb = trf + (size_t)b * S * 12;
    for (int e = threadIdx.x; e < S * 12; e += 256) {
        int s = e / 12, j = e - s * 12;
        float v = tb[e];
        if ((j & 3) == (j >> 2)) v += 1.0f;
        As[s * 13 + j] = v;
    }
    __syncthreads();
    const int s   = threadIdx.x & 63;
    const int pos = pos0 + (threadIdx.x >> 6);
    const int hw  = pos % (H * W);
    const int h   = hw / W;
    const int w   = hw - h * W;
    const float* a = &As[s * 13];
    const float fh = (float)h, fw = (float)w, fz = (float)s * ST_RATIO;
    float x = fmaf(a[0], fh, fmaf(a[1], fw, fmaf(a[2],  fz, a[3])));
    float y = fmaf(a[4], fh, fmaf(a[5], fw, fmaf(a[6],  fz, a[7])));
    float z = fmaf(a[8], fh, fmaf(a[9], fw, fmaf(a[10], fz, a[11])));
    x = fminf(fmaxf(x, 0.0f), (float)(H - 1));
    y = fminf(fmaxf(y, 0.0f), (float)(W - 1));
    z = fminf(fmaxf(z, 0.0f), (float)(D - 1));
    const float flx = floorf(x), fly = floorf(y), flz = floorf(z);
    const float dx = x - flx, dy = y - fly, dz = z - flz;
    const int ix0 = (int)flx, iy0 = (int)fly, iz0 = (int)flz;
    const int ix1 = min(ix0 + 1, H - 1);
    const int iy1 = min(iy0 + 1, W - 1);
    const int iz1 = min(iz0 + 1, D - 1);
    const float* vb  = vol + (size_t)b * (H * W * D);
    const float* p00 = vb + (ix0 * W + iy0) * D;
    const float* p01 = vb + (ix0 * W + iy1) * D;
    const float* p10 = vb + (ix1 * W + iy0) * D;
    const float* p11 = vb + (ix1 * W + iy1) * D;
    const float v000 = p00[iz0], v001 = p00[iz1];
    const float v010 = p01[iz0], v011 = p01[iz1];
    const float v100 = p10[iz0], v101 = p10[iz1];
    const float v110 = p11[iz0], v111 = p11[iz1];
    const float c00 = fmaf(dz, v001 - v000, v000);
    const float c01 = fmaf(dz, v011 - v010, v010);
    const float c10 = fmaf(dz, v101 - v100, v100);
    const float c11 = fmaf(dz, v111 - v110, v110);
    const float c0  = fmaf(dy, c01 - c00, c00);
    const float c1  = fmaf(dy, c11 - c10, c10);
    out[(size_t)pos * S + s] = fmaf(dx, c1 - c0, c0);
}

extern "C" void kernel_launch(void* const* d_in, const int* in_sizes, int n_in,
                              void* d_out, int out_size, void* d_ws, size_t ws_size,
                              hipStream_t stream) {
    const float* vol = (const float*)d_in[0];
    const float* trf = (const float*)d_in[1];
    float* out = (float*)d_out;

    const size_t volP_bytes = (size_t)B * H * D * W * sizeof(__half2);  // 78.6 MB
    if (ws_size >= volP_bytes) {
        __half2* volP = (__half2*)d_ws;
        v2s_prep4<<<B * H * 2, 256, 0, stream>>>(vol, volP);
        v2s_main5<<<3200, 256, 0, stream>>>(volP, trf, out);
    } else {
        v2s_fallback<<<(B * H * W) / 4, 256, 0, stream>>>(vol, trf, out);
    }
}